// Round 2
// 441.731 us; speedup vs baseline: 1.4387x; 1.4387x over previous
//
#include <hip/hip_runtime.h>
#include <float.h>
#include <math.h>

#define NUM_T 8192
#define NUM_E 256
#define HID   7168

typedef __attribute__((ext_vector_type(16))) float f32x16;
typedef __attribute__((ext_vector_type(4))) _Float16 f16x4;
typedef __attribute__((ext_vector_type(8))) _Float16 f16x8;

#define MFMA(a, b, c) __builtin_amdgcn_mfma_f32_32x32x16_f16(a, b, c, 0, 0, 0)

// ---------------------------------------------------------------------------
// LDS layout: row = 64 f16 = 128 B = 16 chunks of 8 B (4 f16).
// Row r holds k=0..31 hi (chunks 0..7) then k=0..31 lo (chunks 8..15).
// 8B-chunk XOR swizzle: chunk' = chunk ^ (r & 15)  (write and read agree).
// X rows 0..127, W rows 128..383. Per buffer 384*128B = 48 KB; dbuf = 96 KB.
// ---------------------------------------------------------------------------
__device__ __forceinline__ int lds_off(int row, int c8) {
  return (row << 6) + ((c8 ^ (row & 15)) << 2);
}

// fp32 -> fp16 hi + fp16 lo. fp16 split: |x - hi - lo| <= 2^-22 |x|, so the
// 3-product scheme (hh + hl + lh) has per-term error ~3*2^-22*|xw| -> logit
// noise ~5e-7, an order of magnitude BELOW fp32 summation-reorder noise
// (the bf16 split's 2^-18 terms flipped top-k ties vs the fp32 reference).
// x - hi is exact in fp32 (hi has 11-bit mantissa, same binade).
__device__ __forceinline__ void cvt4(float4 v, f16x4& h, f16x4& l) {
  h[0] = (_Float16)v.x; h[1] = (_Float16)v.y;
  h[2] = (_Float16)v.z; h[3] = (_Float16)v.w;
  l[0] = (_Float16)(v.x - (float)h[0]);
  l[1] = (_Float16)(v.y - (float)h[1]);
  l[2] = (_Float16)(v.z - (float)h[2]);
  l[3] = (_Float16)(v.w - (float)h[3]);
}

__device__ __forceinline__ f16x8 frag(const _Float16* buf, int row, int c8) {
  const f16x4 p0 = *reinterpret_cast<const f16x4*>(buf + lds_off(row, c8));
  const f16x4 p1 = *reinterpret_cast<const f16x4*>(buf + lds_off(row, c8 + 1));
  return __builtin_shufflevector(p0, p1, 0, 1, 2, 3, 4, 5, 6, 7);
}

// ---------------------------------------------------------------------------
// Kernel 1: router logits via f16x3 split-precision MFMA.
// C = X @ W^T computed as Xhi*Whi + Xhi*Wlo + Xlo*Whi (fp32 accumulate).
// Block: 128 tokens x 256 experts x kLen, BK=32, 8 waves (2x4), wave=64x64.
// Grid 1D; decode puts one split-k slice per XCD pair so the 1.84 MB W
// k-slice stays L2-resident. 2-phase reg-staged double buffer.
// ---------------------------------------------------------------------------
template <int S>
__global__ __launch_bounds__(512, 2) void router_gemm_mfma(
    const float* __restrict__ X, const float* __restrict__ W,
    float* __restrict__ partial) {
  __shared__ _Float16 smem[2][384 * 64];  // 96 KB

  const int tid = threadIdx.x;
  const int bid = blockIdx.x;
  int bx, by;
  if (S == 4) {  // xcd pair <-> split-k slice (consecutive bids round-robin XCDs)
    const int xcd = bid & 7;
    by = xcd >> 1;
    bx = (bid >> 3) * 2 + (xcd & 1);
  } else if (S == 2) {
    const int xcd = bid & 7;
    by = xcd >> 2;
    bx = (bid >> 3) * 4 + (xcd & 3);
  } else {
    by = 0;
    bx = bid;
  }

  const int kLen = HID / S;
  const int nch = kLen / 32;
  const int t0 = bx * 128;
  const int k0 = by * kLen;

  // --- staging geometry -----------------------------------------------------
  const int xr = tid >> 2, xq = tid & 3;  // X: row 0..127, k-quadpair 0..3
  const int wr = tid >> 1, wq = tid & 1;  // W: row 0..255, k-half 0..1
  const float* Xp = X + (size_t)(t0 + xr) * HID + k0 + xq * 8;
  const float* Wp = W + (size_t)wr * HID + k0 + wq * 16;

  int xo[4], wo[8];
  xo[0] = lds_off(xr, xq * 2);
  xo[1] = lds_off(xr, xq * 2 + 1);
  xo[2] = lds_off(xr, 8 + xq * 2);
  xo[3] = lds_off(xr, 8 + xq * 2 + 1);
#pragma unroll
  for (int j = 0; j < 4; ++j) {
    wo[j] = lds_off(128 + wr, wq * 4 + j);
    wo[4 + j] = lds_off(128 + wr, 8 + wq * 4 + j);
  }

  // --- compute geometry -----------------------------------------------------
  const int l = tid & 63, wave = tid >> 6;
  const int wm = wave >> 2, wn = wave & 3;  // 2 x 4 waves of 64x64
  const int la = l & 31, kh = l >> 5;
  const int ar0 = wm * 64 + la;        // A rows (tokens), +32 for 2nd tile
  const int br0 = 128 + wn * 64 + la;  // B rows (experts)

  f32x16 acc[2][2];
#pragma unroll
  for (int i = 0; i < 2; ++i)
#pragma unroll
    for (int j = 0; j < 2; ++j)
#pragma unroll
      for (int r = 0; r < 16; ++r) acc[i][j][r] = 0.f;

  float4 xv[2], wv[4];

#define LOADC()                                            \
  do {                                                     \
    xv[0] = *reinterpret_cast<const float4*>(Xp);          \
    xv[1] = *reinterpret_cast<const float4*>(Xp + 4);      \
    wv[0] = *reinterpret_cast<const float4*>(Wp);          \
    wv[1] = *reinterpret_cast<const float4*>(Wp + 4);      \
    wv[2] = *reinterpret_cast<const float4*>(Wp + 8);      \
    wv[3] = *reinterpret_cast<const float4*>(Wp + 12);     \
    Xp += 32;                                              \
    Wp += 32;                                              \
  } while (0)

#define STAGE(dst)                                         \
  do {                                                     \
    f16x4 h_, l_;                                          \
    cvt4(xv[0], h_, l_);                                   \
    *reinterpret_cast<f16x4*>((dst) + xo[0]) = h_;         \
    *reinterpret_cast<f16x4*>((dst) + xo[2]) = l_;         \
    cvt4(xv[1], h_, l_);                                   \
    *reinterpret_cast<f16x4*>((dst) + xo[1]) = h_;         \
    *reinterpret_cast<f16x4*>((dst) + xo[3]) = l_;         \
    _Pragma("unroll") for (int j = 0; j < 4; ++j) {        \
      cvt4(wv[j], h_, l_);                                 \
      *reinterpret_cast<f16x4*>((dst) + wo[j]) = h_;       \
      *reinterpret_cast<f16x4*>((dst) + wo[4 + j]) = l_;   \
    }                                                      \
  } while (0)

  // prologue: stage chunk 0
  LOADC();
  STAGE(&smem[0][0]);
  __syncthreads();

  int cur = 0;
  for (int c = 0; c < nch; ++c) {
    const bool more = (c + 1) < nch;
    if (more) LOADC();  // in flight across the MFMA phase

    const _Float16* buf = &smem[cur][0];
#pragma unroll
    for (int ks = 0; ks < 2; ++ks) {
      const int cb = ks * 4 + kh * 2;
      f16x8 ah0 = frag(buf, ar0, cb);
      f16x8 ah1 = frag(buf, ar0 + 32, cb);
      f16x8 bh0 = frag(buf, br0, cb);
      f16x8 bh1 = frag(buf, br0 + 32, cb);
      f16x8 al0 = frag(buf, ar0, cb + 8);
      f16x8 al1 = frag(buf, ar0 + 32, cb + 8);
      f16x8 bl0 = frag(buf, br0, cb + 8);
      f16x8 bl1 = frag(buf, br0 + 32, cb + 8);
      acc[0][0] = MFMA(ah0, bh0, acc[0][0]);
      acc[0][1] = MFMA(ah0, bh1, acc[0][1]);
      acc[1][0] = MFMA(ah1, bh0, acc[1][0]);
      acc[1][1] = MFMA(ah1, bh1, acc[1][1]);
      acc[0][0] = MFMA(ah0, bl0, acc[0][0]);
      acc[0][1] = MFMA(ah0, bl1, acc[0][1]);
      acc[1][0] = MFMA(ah1, bl0, acc[1][0]);
      acc[1][1] = MFMA(ah1, bl1, acc[1][1]);
      acc[0][0] = MFMA(al0, bh0, acc[0][0]);
      acc[0][1] = MFMA(al0, bh1, acc[0][1]);
      acc[1][0] = MFMA(al1, bh0, acc[1][0]);
      acc[1][1] = MFMA(al1, bh1, acc[1][1]);
    }

    if (more) STAGE(&smem[cur ^ 1][0]);
    __syncthreads();
    cur ^= 1;
  }

  // epilogue: verified C/D layout for 32x32: col = lane&31,
  // row = (reg&3) + 8*(reg>>2) + 4*(lane>>5)
  float* out = partial + (size_t)by * NUM_T * NUM_E;
#pragma unroll
  for (int ti = 0; ti < 2; ++ti)
#pragma unroll
    for (int tj = 0; tj < 2; ++tj) {
      const int col = wn * 64 + tj * 32 + la;
      const int rb = t0 + wm * 64 + ti * 32 + 4 * kh;
#pragma unroll
      for (int r = 0; r < 16; ++r) {
        const int row = rb + (r & 3) + 8 * (r >> 2);
        out[(size_t)row * NUM_E + col] = acc[ti][tj][r];
      }
    }
#undef LOADC
#undef STAGE
}

// ---------------------------------------------------------------------------
// Kernel 2: per-token selection, one wave per token (unchanged; correctness-
// verified against jax tie-break semantics).
// ---------------------------------------------------------------------------
__global__ __launch_bounds__(256) void router_select(
    const float* __restrict__ partial, int splitk,
    const float* __restrict__ bias, float* __restrict__ outIdx,
    float* __restrict__ outW) {
  const int lane = threadIdx.x & 63;
  const int t = blockIdx.x * 4 + (threadIdx.x >> 6);

  float lg[4] = {0.f, 0.f, 0.f, 0.f};
  for (int s = 0; s < splitk; ++s) {
    const float4 p = *reinterpret_cast<const float4*>(
        partial + ((size_t)s * NUM_T + t) * NUM_E + lane * 4);
    lg[0] += p.x;
    lg[1] += p.y;
    lg[2] += p.z;
    lg[3] += p.w;
  }
  const float4 bv = *reinterpret_cast<const float4*>(bias + lane * 4);

  float sc[4], bs[4];
#pragma unroll
  for (int j = 0; j < 4; ++j) {
    sc[j] = 1.0f / (1.0f + expf(-lg[j]));
  }
  bs[0] = sc[0] + bv.x;
  bs[1] = sc[1] + bv.y;
  bs[2] = sc[2] + bv.z;
  bs[3] = sc[3] + bv.w;

  const int myg = lane >> 3;
  float gsum = bs[0] + bs[1] + bs[2] + bs[3];
#pragma unroll
  for (int d = 1; d < 8; d <<= 1) gsum += __shfl_xor(gsum, d);

  float gsv[8];
#pragma unroll
  for (int g = 0; g < 8; ++g) gsv[g] = __shfl(gsum, g * 8);

  unsigned selm = 0;
  int myrank = 0;
#pragma unroll
  for (int r = 0; r < 4; ++r) {
    int best = -1;
    float bvv = -FLT_MAX;
#pragma unroll
    for (int g = 0; g < 8; ++g) {
      if (!((selm >> g) & 1u) && gsv[g] > bvv) {
        bvv = gsv[g];
        best = g;
      }
    }
    selm |= 1u << best;
    if (best == myg) myrank = r;
  }
  const bool gsel = ((selm >> myg) & 1u) != 0u;

  float myv[4];
#pragma unroll
  for (int j = 0; j < 4; ++j) myv[j] = gsel ? bs[j] : -FLT_MAX;

  const int ebase = lane << 2;
  const int flatb = myrank * 32 + (lane & 7) * 4;

  float chosen_s = 0.f;
  int ex_out = 0;
  float ssum = 0.f;
  for (int r = 0; r < 8; ++r) {
    float v = -FLT_MAX;
    int fl = 1 << 30;
    int ex = 0;
    float s = 0.f;
#pragma unroll
    for (int j = 0; j < 4; ++j) {
      const bool better = (myv[j] > v) || (myv[j] == v && (flatb + j) < fl);
      if (better) {
        v = myv[j];
        fl = flatb + j;
        ex = ebase + j;
        s = sc[j];
      }
    }
#pragma unroll
    for (int d = 32; d > 0; d >>= 1) {
      const float v2 = __shfl_xor(v, d);
      const int fl2 = __shfl_xor(fl, d);
      const int ex2 = __shfl_xor(ex, d);
      const float s2 = __shfl_xor(s, d);
      if (v2 > v || (v2 == v && fl2 < fl)) {
        v = v2;
        fl = fl2;
        ex = ex2;
        s = s2;
      }
    }
    ssum += s;
    if (lane == r) {
      chosen_s = s;
      ex_out = ex;
    }
    if ((ex >> 2) == lane) myv[ex & 3] = -FLT_MAX;
  }

  if (lane < 8) {
    outIdx[t * 8 + lane] = (float)ex_out;
    outW[t * 8 + lane] = chosen_s / (ssum + 1e-20f) * 2.5f;
  }
}

extern "C" void kernel_launch(void* const* d_in, const int* in_sizes, int n_in,
                              void* d_out, int out_size, void* d_ws,
                              size_t ws_size, hipStream_t stream) {
  const float* X = (const float*)d_in[0];     // [8192, 7168]
  const float* W = (const float*)d_in[1];     // [256, 7168]
  const float* bias = (const float*)d_in[2];  // [256]
  float* partial = (float*)d_ws;

  const size_t slice = (size_t)NUM_T * NUM_E * sizeof(float);  // 8.4 MB
  int S;
  if (ws_size >= 4 * slice)
    S = 4;
  else if (ws_size >= 2 * slice)
    S = 2;
  else
    S = 1;

  if (S == 4)
    router_gemm_mfma<4><<<dim3(64 * 4), dim3(512), 0, stream>>>(X, W, partial);
  else if (S == 2)
    router_gemm_mfma<2><<<dim3(64 * 2), dim3(512), 0, stream>>>(X, W, partial);
  else
    router_gemm_mfma<1><<<dim3(64), dim3(512), 0, stream>>>(X, W, partial);

  float* outIdx = (float*)d_out;     // indices as exact float ints
  float* outW = outIdx + NUM_T * 8;  // weights
  router_select<<<NUM_T / 4, 256, 0, stream>>>(partial, S, bias, outIdx, outW);
}

// Round 4
// 387.522 us; speedup vs baseline: 1.6399x; 1.1399x over previous
//
#include <hip/hip_runtime.h>
#include <float.h>
#include <math.h>

#define NUM_T 8192
#define NUM_E 256
#define HID   7168

#define ROWB 136              // LDS row stride (128 B data + 8 B pad -> conflict-free)
#define BUFB (384 * ROWB)     // 52224 B per buffer; 2 buffers = 102 KB

typedef __attribute__((ext_vector_type(16))) float f32x16;
typedef __attribute__((ext_vector_type(4))) _Float16 f16x4;
typedef __attribute__((ext_vector_type(8))) _Float16 f16x8;

#define MFMA(a, b, c) __builtin_amdgcn_mfma_f32_32x32x16_f16(a, b, c, 0, 0, 0)

// lgkm drain (ds writes visible) + barrier; does NOT drain vmcnt, so global
// loads prefetched 2 chunks ahead stay in flight across the barrier.
#define BARRIER() asm volatile("s_waitcnt lgkmcnt(0)\n\ts_barrier" ::: "memory")

// fp32 -> fp16 hi + fp16 lo (identical numerics to the passing round-2 kernel)
__device__ __forceinline__ void cvt4(float4 v, f16x4& h, f16x4& l) {
  h[0] = (_Float16)v.x; h[1] = (_Float16)v.y;
  h[2] = (_Float16)v.z; h[3] = (_Float16)v.w;
  l[0] = (_Float16)(v.x - (float)h[0]);
  l[1] = (_Float16)(v.y - (float)h[1]);
  l[2] = (_Float16)(v.z - (float)h[2]);
  l[3] = (_Float16)(v.w - (float)h[3]);
}

__device__ __forceinline__ f16x8 fr(const char* p, int off) {
  const f16x4 a = *reinterpret_cast<const f16x4*>(p + off);
  const f16x4 b = *reinterpret_cast<const f16x4*>(p + off + 8);
  return __builtin_shufflevector(a, b, 0, 1, 2, 3, 4, 5, 6, 7);
}

struct Q {
  float4 x0, x1, w0, w1, w2, w3;
};

// ---------------------------------------------------------------------------
// Kernel 1: router logits via f16x3 split-precision MFMA.
// C = X @ W^T as Xhi*Whi + Xhi*Wlo + Xlo*Whi (fp32 accumulate).
// Block 128x256xkLen, BK=32, 8 waves (2x4), wave tile 64x64.
// LDS row = 64 f16 (hi chunk 0..7, lo chunk 8..15) + 8 B pad: all frag/stage
// addresses are base-pointer + compile-time immediates (no per-chunk VALU).
// Depth-2 register prefetch (q0/q1), one asm barrier per chunk, no vmcnt
// drain -> memory latency hidden under two full MFMA phases.
// ---------------------------------------------------------------------------
template <int S>
__global__ __launch_bounds__(512, 2) void router_gemm_mfma(
    const float* __restrict__ X, const float* __restrict__ W,
    float* __restrict__ partial) {
  __shared__ __align__(16) char lds[2 * BUFB];  // 102 KB -> 1 block/CU

  const int tid = threadIdx.x;
  const int bid = blockIdx.x;
  int bx, by;
  if (S == 4) {  // split-k slice <-> XCD pair: W k-slice (1.84 MB) L2-resident
    const int xcd = bid & 7;
    by = xcd >> 1;
    bx = (bid >> 3) * 2 + (xcd & 1);
  } else if (S == 2) {
    const int xcd = bid & 7;
    by = xcd >> 2;
    bx = (bid >> 3) * 4 + (xcd & 3);
  } else {
    by = 0;
    bx = bid;
  }

  const int kLen = HID / S;
  const int nch = kLen / 32;  // 56 / 112 / 224 -- always even
  const int t0 = bx * 128;
  const int k0 = by * kLen;

  // --- staging geometry ----------------------------------------------------
  const int xr = tid >> 2, xq = tid & 3;  // X: row 0..127, k-quad 0..3
  const int wr = tid >> 1, wq = tid & 1;  // W: row 0..255, k-half 0..1
  const float* Xp = X + (size_t)(t0 + xr) * HID + k0 + xq * 8;
  const float* Wp = W + (size_t)wr * HID + k0 + wq * 16;
  char* wx = lds + xr * ROWB + xq * 16;          // X write base (hi; lo at +64)
  char* ww = lds + (128 + wr) * ROWB + wq * 32;  // W write base

  // --- compute geometry ----------------------------------------------------
  const int l = tid & 63, wave = tid >> 6;
  const int wm = wave >> 2, wn = wave & 3;  // 2x4 waves of 64x64
  const int la = l & 31, kh = l >> 5;
  // frag k-octet: chunk cb = ks*4 + kh*2 -> byte ks*32 + kh*16 (kh folded here)
  const char* ra = lds + (wm * 64 + la) * ROWB + kh * 16;
  const char* rb = lds + (128 + wn * 64 + la) * ROWB + kh * 16;

  f32x16 acc[2][2];
#pragma unroll
  for (int i = 0; i < 2; ++i)
#pragma unroll
    for (int j = 0; j < 2; ++j)
#pragma unroll
      for (int r = 0; r < 16; ++r) acc[i][j][r] = 0.f;

#define LOADC(q)                                   \
  do {                                             \
    q.x0 = *reinterpret_cast<const float4*>(Xp);   \
    q.x1 = *reinterpret_cast<const float4*>(Xp + 4); \
    q.w0 = *reinterpret_cast<const float4*>(Wp);   \
    q.w1 = *reinterpret_cast<const float4*>(Wp + 4); \
    q.w2 = *reinterpret_cast<const float4*>(Wp + 8); \
    q.w3 = *reinterpret_cast<const float4*>(Wp + 12); \
    Xp += 32;                                      \
    Wp += 32;                                      \
  } while (0)

#define STAGE(B, q)                                            \
  do {                                                         \
    f16x4 h_, l_;                                              \
    cvt4(q.x0, h_, l_);                                        \
    *reinterpret_cast<f16x4*>(wx + (B) + 0) = h_;              \
    *reinterpret_cast<f16x4*>(wx + (B) + 64) = l_;             \
    cvt4(q.x1, h_, l_);                                        \
    *reinterpret_cast<f16x4*>(wx + (B) + 8) = h_;              \
    *reinterpret_cast<f16x4*>(wx + (B) + 72) = l_;             \
    cvt4(q.w0, h_, l_);                                        \
    *reinterpret_cast<f16x4*>(ww + (B) + 0) = h_;              \
    *reinterpret_cast<f16x4*>(ww + (B) + 64) = l_;             \
    cvt4(q.w1, h_, l_);                                        \
    *reinterpret_cast<f16x4*>(ww + (B) + 8) = h_;              \
    *reinterpret_cast<f16x4*>(ww + (B) + 72) = l_;             \
    cvt4(q.w2, h_, l_);                                        \
    *reinterpret_cast<f16x4*>(ww + (B) + 16) = h_;             \
    *reinterpret_cast<f16x4*>(ww + (B) + 80) = l_;             \
    cvt4(q.w3, h_, l_);                                        \
    *reinterpret_cast<f16x4*>(ww + (B) + 24) = h_;             \
    *reinterpret_cast<f16x4*>(ww + (B) + 88) = l_;             \
  } while (0)

#define MF_PHASE(B)                                            \
  do {                                                         \
    _Pragma("unroll") for (int ks = 0; ks < 2; ++ks) {         \
      const int o = (B) + ks * 32;                             \
      f16x8 ah0 = fr(ra, o);                                   \
      f16x8 ah1 = fr(ra, o + 32 * ROWB);                       \
      f16x8 bh0 = fr(rb, o);                                   \
      f16x8 bh1 = fr(rb, o + 32 * ROWB);                       \
      f16x8 al0 = fr(ra, o + 64);                              \
      f16x8 al1 = fr(ra, o + 64 + 32 * ROWB);                  \
      f16x8 bl0 = fr(rb, o + 64);                              \
      f16x8 bl1 = fr(rb, o + 64 + 32 * ROWB);                  \
      acc[0][0] = MFMA(ah0, bh0, acc[0][0]);                   \
      acc[0][1] = MFMA(ah0, bh1, acc[0][1]);                   \
      acc[1][0] = MFMA(ah1, bh0, acc[1][0]);                   \
      acc[1][1] = MFMA(ah1, bh1, acc[1][1]);                   \
      acc[0][0] = MFMA(ah0, bl0, acc[0][0]);                   \
      acc[0][1] = MFMA(ah0, bl1, acc[0][1]);                   \
      acc[1][0] = MFMA(ah1, bl0, acc[1][0]);                   \
      acc[1][1] = MFMA(ah1, bl1, acc[1][1]);                   \
      acc[0][0] = MFMA(al0, bh0, acc[0][0]);                   \
      acc[0][1] = MFMA(al0, bh1, acc[0][1]);                   \
      acc[1][0] = MFMA(al1, bh0, acc[1][0]);                   \
      acc[1][1] = MFMA(al1, bh1, acc[1][1]);                   \
    }                                                          \
  } while (0)

  Q q0, q1;
  LOADC(q0);          // chunk 0
  LOADC(q1);          // chunk 1
  STAGE(0, q0);       // stage chunk 0 (auto counted vmcnt for q0 only)
  BARRIER();

  for (int c = 0; c < nch; c += 2) {
    // even chunk c: compute buf0, stage chunk c+1 into buf1
    if (c + 2 < nch) LOADC(q0);  // chunk c+2 in flight for 2 phases
    MF_PHASE(0);
    STAGE(BUFB, q1);
    BARRIER();
    // odd chunk c+1: compute buf1, stage chunk c+2 into buf0
    if (c + 3 < nch) LOADC(q1);  // chunk c+3
    MF_PHASE(BUFB);
    if (c + 2 < nch) STAGE(0, q0);
    BARRIER();
  }

  // epilogue: C/D layout for 32x32: col = lane&31, row = (r&3)+8*(r>>2)+4*kh
  float* out = partial + (size_t)by * NUM_T * NUM_E;
#pragma unroll
  for (int ti = 0; ti < 2; ++ti)
#pragma unroll
    for (int tj = 0; tj < 2; ++tj) {
      const int col = wn * 64 + tj * 32 + la;
      const int rbse = t0 + wm * 64 + ti * 32 + 4 * kh;
#pragma unroll
      for (int r = 0; r < 16; ++r) {
        const int row = rbse + (r & 3) + 8 * (r >> 2);
        out[(size_t)row * NUM_E + col] = acc[ti][tj][r];
      }
    }
#undef LOADC
#undef STAGE
#undef MF_PHASE
}

// ---------------------------------------------------------------------------
// Kernel 2: per-token selection, one wave per token (unchanged, verified).
// ---------------------------------------------------------------------------
__global__ __launch_bounds__(256) void router_select(
    const float* __restrict__ partial, int splitk,
    const float* __restrict__ bias, float* __restrict__ outIdx,
    float* __restrict__ outW) {
  const int lane = threadIdx.x & 63;
  const int t = blockIdx.x * 4 + (threadIdx.x >> 6);

  float lg[4] = {0.f, 0.f, 0.f, 0.f};
  for (int s = 0; s < splitk; ++s) {
    const float4 p = *reinterpret_cast<const float4*>(
        partial + ((size_t)s * NUM_T + t) * NUM_E + lane * 4);
    lg[0] += p.x;
    lg[1] += p.y;
    lg[2] += p.z;
    lg[3] += p.w;
  }
  const float4 bv = *reinterpret_cast<const float4*>(bias + lane * 4);

  float sc[4], bs[4];
#pragma unroll
  for (int j = 0; j < 4; ++j) {
    sc[j] = 1.0f / (1.0f + expf(-lg[j]));
  }
  bs[0] = sc[0] + bv.x;
  bs[1] = sc[1] + bv.y;
  bs[2] = sc[2] + bv.z;
  bs[3] = sc[3] + bv.w;

  const int myg = lane >> 3;
  float gsum = bs[0] + bs[1] + bs[2] + bs[3];
#pragma unroll
  for (int d = 1; d < 8; d <<= 1) gsum += __shfl_xor(gsum, d);

  float gsv[8];
#pragma unroll
  for (int g = 0; g < 8; ++g) gsv[g] = __shfl(gsum, g * 8);

  unsigned selm = 0;
  int myrank = 0;
#pragma unroll
  for (int r = 0; r < 4; ++r) {
    int best = -1;
    float bvv = -FLT_MAX;
#pragma unroll
    for (int g = 0; g < 8; ++g) {
      if (!((selm >> g) & 1u) && gsv[g] > bvv) {
        bvv = gsv[g];
        best = g;
      }
    }
    selm |= 1u << best;
    if (best == myg) myrank = r;
  }
  const bool gsel = ((selm >> myg) & 1u) != 0u;

  float myv[4];
#pragma unroll
  for (int j = 0; j < 4; ++j) myv[j] = gsel ? bs[j] : -FLT_MAX;

  const int ebase = lane << 2;
  const int flatb = myrank * 32 + (lane & 7) * 4;

  float chosen_s = 0.f;
  int ex_out = 0;
  float ssum = 0.f;
  for (int r = 0; r < 8; ++r) {
    float v = -FLT_MAX;
    int fl = 1 << 30;
    int ex = 0;
    float s = 0.f;
#pragma unroll
    for (int j = 0; j < 4; ++j) {
      const bool better = (myv[j] > v) || (myv[j] == v && (flatb + j) < fl);
      if (better) {
        v = myv[j];
        fl = flatb + j;
        ex = ebase + j;
        s = sc[j];
      }
    }
#pragma unroll
    for (int d = 32; d > 0; d >>= 1) {
      const float v2 = __shfl_xor(v, d);
      const int fl2 = __shfl_xor(fl, d);
      const int ex2 = __shfl_xor(ex, d);
      const float s2 = __shfl_xor(s, d);
      if (v2 > v || (v2 == v && fl2 < fl)) {
        v = v2;
        fl = fl2;
        ex = ex2;
        s = s2;
      }
    }
    ssum += s;
    if (lane == r) {
      chosen_s = s;
      ex_out = ex;
    }
    if ((ex >> 2) == lane) myv[ex & 3] = -FLT_MAX;
  }

  if (lane < 8) {
    outIdx[t * 8 + lane] = (float)ex_out;
    outW[t * 8 + lane] = chosen_s / (ssum + 1e-20f) * 2.5f;
  }
}

extern "C" void kernel_launch(void* const* d_in, const int* in_sizes, int n_in,
                              void* d_out, int out_size, void* d_ws,
                              size_t ws_size, hipStream_t stream) {
  const float* X = (const float*)d_in[0];     // [8192, 7168]
  const float* W = (const float*)d_in[1];     // [256, 7168]
  const float* bias = (const float*)d_in[2];  // [256]
  float* partial = (float*)d_ws;

  const size_t slice = (size_t)NUM_T * NUM_E * sizeof(float);  // 8.4 MB
  int S;
  if (ws_size >= 4 * slice)
    S = 4;
  else if (ws_size >= 2 * slice)
    S = 2;
  else
    S = 1;

  if (S == 4)
    router_gemm_mfma<4><<<dim3(64 * 4), dim3(512), 0, stream>>>(X, W, partial);
  else if (S == 2)
    router_gemm_mfma<2><<<dim3(64 * 2), dim3(512), 0, stream>>>(X, W, partial);
  else
    router_gemm_mfma<1><<<dim3(64), dim3(512), 0, stream>>>(X, W, partial);

  float* outIdx = (float*)d_out;     // indices as exact float ints
  float* outW = outIdx + NUM_T * 8;  // weights
  router_select<<<NUM_T / 4, 256, 0, stream>>>(partial, S, bias, outIdx, outW);
}